// Round 5
// baseline (3354.205 us; speedup 1.0000x reference)
//
#include <hip/hip_runtime.h>
#include <stdint.h>
#include <stddef.h>

#define B_ 64
#define L_ 200
#define F_ 512
#define H_ 512
#define A_ 512
#define E_ 512
#define V_ 50257
#define T_ 21
#define D_ 1024
#define NBLK_LOG 786   /* ceil(V/64) */
#define BH (B_ * H_)
#define NROW 1280      /* 20 planes x 64 batch */

typedef __attribute__((ext_vector_type(8))) short short8;
typedef __attribute__((ext_vector_type(4))) float f32x4;

__device__ __forceinline__ unsigned short f2b(float f) {
  unsigned int u = __builtin_bit_cast(unsigned int, f);
  u += 0x7FFFu + ((u >> 16) & 1u);
  return (unsigned short)(u >> 16);
}
__device__ __forceinline__ float b2f(unsigned short s) {
  unsigned int u = ((unsigned int)s) << 16;
  return __builtin_bit_cast(float, u);
}
__device__ __forceinline__ f32x4 mfma16(short8 a, short8 b, f32x4 c) {
  return __builtin_amdgcn_mfma_f32_16x16x32_bf16(a, b, c, 0, 0, 0);
}
// fragment-ordered layouts (wave-contiguous MFMA operand loads)
__device__ __forceinline__ int hsoff(int b, int j) {  // H=512 plane
  return (((b >> 4) * 16 + (j >> 5)) * 64 + (((j >> 3) & 3) * 16 + (b & 15))) * 8 + (j & 7);
}
__device__ __forceinline__ int xoff(int b, int k) {   // D=1024 x-plane
  return (((b >> 4) * 32 + (k >> 5)) * 64 + (((k >> 3) & 3) * 16 + (b & 15))) * 8 + (k & 7);
}

/* ---------------- setup kernels ---------------- */

__global__ void k_cvt(const float* __restrict__ src, unsigned short* __restrict__ dst, int n4) {
  int i = blockIdx.x * blockDim.x + threadIdx.x;
  int stride = gridDim.x * blockDim.x;
  const float4* s4 = (const float4*)src;
  ushort4* d4 = (ushort4*)dst;
  for (; i < n4; i += stride) {
    float4 v = s4[i];
    ushort4 o;
    o.x = f2b(v.x); o.y = f2b(v.y); o.z = f2b(v.z); o.w = f2b(v.w);
    d4[i] = o;
  }
}

// W f32 (R,K) row-major -> fragment-ordered bf16 ; grid R/16 blocks
__global__ void k_wfrag(const float* __restrict__ src, unsigned short* __restrict__ dst, int K) {
  int rt = blockIdx.x;
  int r15 = threadIdx.x & 15;
  int row = rt * 16 + r15;
  int nch = K >> 3;
  int kpw = K >> 5;
  for (int kc = threadIdx.x >> 4; kc < nch; kc += 16) {
    const float4* s = (const float4*)(src + (size_t)row * K + kc * 8);
    float4 x = s[0], y = s[1];
    short8 o;
    o[0] = f2b(x.x); o[1] = f2b(x.y); o[2] = f2b(x.z); o[3] = f2b(x.w);
    o[4] = f2b(y.x); o[5] = f2b(y.y); o[6] = f2b(y.z); o[7] = f2b(y.w);
    *(short8*)(dst + ((size_t)(rt * kpw + (kc >> 2)) * 64 + ((kc & 3) * 16 + r15)) * 8) = o;
  }
}

// src f32 (R,C) -> dst bf16 (C,R); R,C multiples of 64; grid (C/64, R/64), 256 thr
__global__ void k_transcvt(const float* __restrict__ src, unsigned short* __restrict__ dst, int R, int C) {
  __shared__ float tile[64][65];
  int cb = blockIdx.x * 64, rb = blockIdx.y * 64;
  int tx = threadIdx.x & 63, ty = threadIdx.x >> 6;
#pragma unroll
  for (int i = 0; i < 16; ++i) {
    int r = ty * 16 + i;
    tile[r][tx] = src[(size_t)(rb + r) * C + cb + tx];
  }
  __syncthreads();
#pragma unroll
  for (int i = 0; i < 16; ++i) {
    int c = ty * 16 + i;
    dst[(size_t)(cb + c) * R + rb + tx] = f2b(tile[tx][c]);
  }
}

// src f32 (R,C) -> dst f32 (C,R); grid (C/64, R/64)
__global__ void k_trans32(const float* __restrict__ src, float* __restrict__ dst, int R, int C) {
  __shared__ float tile[64][65];
  int cb = blockIdx.x * 64, rb = blockIdx.y * 64;
  int tx = threadIdx.x & 63, ty = threadIdx.x >> 6;
#pragma unroll
  for (int i = 0; i < 16; ++i) {
    int r = ty * 16 + i;
    tile[r][tx] = src[(size_t)(rb + r) * C + cb + tx];
  }
  __syncthreads();
#pragma unroll
  for (int i = 0; i < 16; ++i) {
    int c = ty * 16 + i;
    dst[(size_t)(cb + c) * R + rb + tx] = tile[tx][c];
  }
}

// dih (B,H) f32 -> hs fragment layout (plane 0) ; grid 64
__global__ void k_hs0(const float* __restrict__ src, unsigned short* __restrict__ hs) {
  int b = blockIdx.x;
  for (int j = threadIdx.x; j < H_; j += 256)
    hs[hsoff(b, j)] = f2b(src[(size_t)b * H_ + j]);
}

// epb[(b,l)][a] = sum_f encb[(b,l)][f] * WaTb[a][f] ; grid 200 blocks (64 rows each)
__global__ __launch_bounds__(256, 2) void k_encproj2(const unsigned short* __restrict__ encb,
                                                     const unsigned short* __restrict__ WaTb,
                                                     unsigned short* __restrict__ epb) {
  __shared__ unsigned short al[32768];  // 64 rows x 1024B, XOR-swizzled
  int tid = threadIdx.x;
  size_t rowbase = (size_t)blockIdx.x * 64;
  for (int idx = tid; idx < 4096; idx += 256) {
    int row = idx >> 6, seg = idx & 63;
    unsigned char* dp = (unsigned char*)al + row * 1024 + ((seg * 16) ^ ((row & 7) << 4));
    *(short8*)dp = *(const short8*)(encb + (rowbase + row) * F_ + seg * 8);
  }
  __syncthreads();
  int w = tid >> 6, lane = tid & 63, ln15 = lane & 15, g = lane >> 4;
  int sw = (ln15 & 7) << 4;
  const unsigned char* alb = (const unsigned char*)al;
  int mrow = w * 16 + ln15;
  for (int nt = 0; nt < 32; ++nt) {
    f32x4 acc = {0.f, 0.f, 0.f, 0.f};
    const unsigned short* brow = WaTb + (size_t)(nt * 16 + ln15) * F_ + 8 * g;
#pragma unroll 4
    for (int kk = 0; kk < 16; ++kk) {
      short8 bf = *(const short8*)(brow + kk * 32);
      short8 af = *(const short8*)(alb + mrow * 1024 + ((kk * 64 + 16 * g) ^ sw));
      acc = mfma16(af, bf, acc);
    }
#pragma unroll
    for (int r = 0; r < 4; ++r) {
      size_t m = rowbase + w * 16 + 4 * g + r;
      epb[m * A_ + nt * 16 + ln15] = f2b(acc[r]);
    }
  }
}

// out[:,0,:] = 0 ; grid (50, 64), 256 thr
__global__ void k_zero0(float* __restrict__ out) {
  int b = blockIdx.y;
  float* o = out + (size_t)b * T_ * V_;
  int v0 = blockIdx.x * 1024 + threadIdx.x;
#pragma unroll
  for (int i = 0; i < 4; ++i) { int v = v0 + i * 256; if (v < V_) o[v] = 0.f; }
}

/* ---------------- params ---------------- */

struct RecParams {
  const float* mask; const float* et;
  const unsigned short* encb; const unsigned short* epb;
  const unsigned short* WahT; const float* vatt;
  const unsigned short* Wfih; const unsigned short* Wfhh;
  const float* bih; const float* bhh;
  const unsigned short* Wb; const float* bout;
  const int* ref;
  unsigned short* xbf;
  float* pm; float* ps; float* lse;
  float* out;
};

/* ---------------- per-step kernels ---------------- */

// attention for step ts, one block per batch
__global__ __launch_bounds__(256) void k_att(RecParams P, const unsigned short* __restrict__ hs,
                                             int ts) {
  __shared__ struct {
    float hrow[H_];
    float hw[A_];
    float sc[256];
    float ctxp[4][F_];
  } S;
  int b = blockIdx.x;
  int tid = threadIdx.x;
  int w = tid >> 6, lane = tid & 63;
  int word = P.ref[b * T_ + ts];
  const float* er = P.et + (size_t)word * E_;
  // emb -> xbf fragment-ordered (16B chunks)
  for (int c = tid; c < 64; c += 256) {
    const float4* s = (const float4*)(er + c * 8);
    float4 x = s[0], y = s[1];
    short8 o;
    o[0] = f2b(x.x); o[1] = f2b(x.y); o[2] = f2b(x.z); o[3] = f2b(x.w);
    o[4] = f2b(y.x); o[5] = f2b(y.y); o[6] = f2b(y.z); o[7] = f2b(y.w);
    *(short8*)(P.xbf + xoff(b, c * 8)) = o;
  }
  for (int k = tid; k < H_; k += 256) S.hrow[k] = b2f(hs[hsoff(b, k)]);
  __syncthreads();
  // hW matvec: wave-per-row (coalesced full-row loads)
  float hl[8];
#pragma unroll
  for (int j = 0; j < 8; ++j) hl[j] = S.hrow[lane * 8 + j];
  for (int a = w; a < A_; a += 4) {
    short8 wv = *(const short8*)(P.WahT + (size_t)a * H_ + lane * 8);
    float p = 0.f;
#pragma unroll
    for (int j = 0; j < 8; ++j) p += b2f((unsigned short)wv[j]) * hl[j];
    for (int o = 1; o < 64; o <<= 1) p += __shfl_xor(p, o);
    if (lane == 0) S.hw[a] = p;
  }
  __syncthreads();
  float hwv[8], vv[8];
#pragma unroll
  for (int j = 0; j < 8; ++j) { hwv[j] = S.hw[lane * 8 + j]; vv[j] = P.vatt[lane * 8 + j]; }
  for (int l = w; l < L_; l += 4) {
    short8 ev = *(const short8*)(P.epb + ((size_t)b * L_ + l) * A_ + lane * 8);
    float p = 0.f;
#pragma unroll
    for (int j = 0; j < 8; ++j) {
      float x = b2f((unsigned short)ev[j]) + hwv[j];
      float e2 = __expf(x + x);
      float th = 1.f - 2.f / (e2 + 1.f);
      p += th * vv[j];
    }
    for (int o = 1; o < 64; o <<= 1) p += __shfl_xor(p, o);
    if (lane == 0) {
      float mk = P.mask[b * L_ + l];
      S.sc[l] = (mk > 0.f) ? p : -1e9f;
    }
  }
  __syncthreads();
  if (tid < 64) {
    float m = -1e30f;
    for (int l = tid; l < L_; l += 64) m = fmaxf(m, S.sc[l]);
    for (int o = 1; o < 64; o <<= 1) m = fmaxf(m, __shfl_xor(m, o));
    float s = 0.f;
    for (int l = tid; l < L_; l += 64) s += __expf(S.sc[l] - m);
    for (int o = 1; o < 64; o <<= 1) s += __shfl_xor(s, o);
    float inv = 1.f / s;
    for (int l = tid; l < L_; l += 64) S.sc[l] = __expf(S.sc[l] - m) * inv;
  }
  __syncthreads();
  float cacc[8] = {0.f, 0.f, 0.f, 0.f, 0.f, 0.f, 0.f, 0.f};
  for (int l = w; l < L_; l += 4) {
    float aw = S.sc[l];
    short8 evv = *(const short8*)(P.encb + ((size_t)b * L_ + l) * F_ + lane * 8);
#pragma unroll
    for (int j = 0; j < 8; ++j) cacc[j] += aw * b2f((unsigned short)evv[j]);
  }
#pragma unroll
  for (int j = 0; j < 8; ++j) S.ctxp[w][lane * 8 + j] = cacc[j];
  __syncthreads();
  // ctx -> xbf fragment-ordered (16B chunks)
  for (int c = tid; c < 64; c += 256) {
    short8 o;
#pragma unroll
    for (int j = 0; j < 8; ++j) {
      int f = c * 8 + j;
      o[j] = f2b(S.ctxp[0][f] + S.ctxp[1][f] + S.ctxp[2][f] + S.ctxp[3][f]);
    }
    *(short8*)(P.xbf + xoff(b, E_ + c * 8)) = o;
  }
}

// GRU cell, 16 j-cols per block ; grid 32 ; all operand loads wave-contiguous
__global__ __launch_bounds__(256) void k_gru(RecParams P,
                                             const unsigned short* __restrict__ hsold,
                                             const float* __restrict__ hTold,
                                             unsigned short* __restrict__ hsnew,
                                             float* __restrict__ hTnew) {
  int bx = blockIdx.x;
  int w = threadIdx.x >> 6, lane = threadIdx.x & 63;
  int ln15 = lane & 15, g = lane >> 4;
  f32x4 z4 = {0.f, 0.f, 0.f, 0.f};
  f32x4 aIr = z4, aIz = z4, aIn = z4, aHr = z4, aHz = z4, aHn = z4;
  {
    const unsigned short* xf = P.xbf;
#pragma unroll 2
    for (int kk = 0; kk < 32; ++kk) {
      short8 xv = *(const short8*)(xf + (((size_t)w * 32 + kk) * 64 + lane) * 8);
      aIr = mfma16(*(const short8*)(P.Wfih + (((size_t)(0 * 32 + bx) * 32 + kk) * 64 + lane) * 8), xv, aIr);
      aIz = mfma16(*(const short8*)(P.Wfih + (((size_t)(32 + bx) * 32 + kk) * 64 + lane) * 8), xv, aIz);
      aIn = mfma16(*(const short8*)(P.Wfih + (((size_t)(64 + bx) * 32 + kk) * 64 + lane) * 8), xv, aIn);
    }
  }
  {
#pragma unroll 2
    for (int kk = 0; kk < 16; ++kk) {
      short8 hv = *(const short8*)(hsold + (((size_t)w * 16 + kk) * 64 + lane) * 8);
      aHr = mfma16(*(const short8*)(P.Wfhh + (((size_t)(0 * 32 + bx) * 16 + kk) * 64 + lane) * 8), hv, aHr);
      aHz = mfma16(*(const short8*)(P.Wfhh + (((size_t)(32 + bx) * 16 + kk) * 64 + lane) * 8), hv, aHz);
      aHn = mfma16(*(const short8*)(P.Wfhh + (((size_t)(64 + bx) * 16 + kk) * 64 + lane) * 8), hv, aHn);
    }
  }
  int jb = bx * 16;
#pragma unroll
  for (int r = 0; r < 4; ++r) {
    int j = jb + 4 * g + r;
    int b = w * 16 + ln15;
    float ir = aIr[r] + P.bih[j];
    float iz = aIz[r] + P.bih[512 + j];
    float in_ = aIn[r] + P.bih[1024 + j];
    float hrv = aHr[r] + P.bhh[j];
    float hzv = aHz[r] + P.bhh[512 + j];
    float hnv = aHn[r] + P.bhh[1024 + j];
    float rg = 1.f / (1.f + __expf(-(ir + hrv)));
    float zg = 1.f / (1.f + __expf(-(iz + hzv)));
    float e2 = __expf(2.f * (in_ + rg * hnv));
    float ng = 1.f - 2.f / (e2 + 1.f);
    float ho = hTold[(size_t)j * B_ + b];
    float hv = (1.f - zg) * ng + zg * ho;
    hTnew[(size_t)j * B_ + b] = hv;
    hsnew[hsoff(b, j)] = f2b(hv);
  }
}

/* ---------------- deferred logits GEMM + LSE partials ---------------- */
// M=1280 (20 planes x 64 batch), K=512, N=50257; Wb tile in registers.
__global__ __launch_bounds__(256) void k_biggemm(RecParams P,
                                                 const unsigned short* __restrict__ hsAll) {
  __shared__ float lpm[4][64], lps[4][64];
  int tid = threadIdx.x;
  int w = tid >> 6, lane = tid & 63;
  int ln15 = lane & 15, g = lane >> 4;
  int vcol = blockIdx.x * 64 + w * 16 + ln15;
  bool vok = vcol < V_;
  int vr = vok ? vcol : (V_ - 1);
  const unsigned short* brow = P.Wb + (size_t)vr * H_ + 8 * g;
  short8 wb[16];
#pragma unroll
  for (int kk = 0; kk < 16; ++kk) wb[kk] = *(const short8*)(brow + kk * 32);
  float bo = P.bout[vr];
  for (int t = 0; t < T_ - 1; ++t) {
    const unsigned short* hp = hsAll + (size_t)(t + 1) * BH;
#pragma unroll
    for (int mp = 0; mp < 2; ++mp) {
      f32x4 z4 = {0.f, 0.f, 0.f, 0.f};
      f32x4 acc[2] = {z4, z4};
#pragma unroll
      for (int kk = 0; kk < 16; ++kk) {
        short8 a0 = *(const short8*)(hp + (((mp * 2 + 0) * 16 + kk) * 64 + lane) * 8);
        short8 a1 = *(const short8*)(hp + (((mp * 2 + 1) * 16 + kk) * 64 + lane) * 8);
        acc[0] = mfma16(a0, wb[kk], acc[0]);
        acc[1] = mfma16(a1, wb[kk], acc[1]);
      }
#pragma unroll
      for (int q = 0; q < 2; ++q) {
        int mt = mp * 2 + q;
#pragma unroll
        for (int r = 0; r < 4; ++r) {
          float val = acc[q][r] + bo;
          int bi = mt * 16 + 4 * g + r;
          if (vok) P.out[((size_t)bi * T_ + (t + 1)) * V_ + vcol] = val;
          float pv = vok ? val : -1e30f;
          float mx = pv;
          for (int o = 1; o < 16; o <<= 1) mx = fmaxf(mx, __shfl_xor(mx, o));
          float e = __expf(pv - mx);
          for (int o = 1; o < 16; o <<= 1) e += __shfl_xor(e, o);
          if (ln15 == 0) { lpm[w][bi] = mx; lps[w][bi] = e; }
        }
      }
    }
    __syncthreads();
    if (tid < 64) {
      float m = fmaxf(fmaxf(lpm[0][tid], lpm[1][tid]), fmaxf(lpm[2][tid], lpm[3][tid]));
      float se = lps[0][tid] * __expf(lpm[0][tid] - m) + lps[1][tid] * __expf(lpm[1][tid] - m) +
                 lps[2][tid] * __expf(lpm[2][tid] - m) + lps[3][tid] * __expf(lpm[3][tid] - m);
      size_t rho = (size_t)t * 64 + tid;
      P.pm[rho * NBLK_LOG + blockIdx.x] = m;
      P.ps[rho * NBLK_LOG + blockIdx.x] = se;
    }
    __syncthreads();
  }
}

// merge partials -> lse[rho] ; grid 1280
__global__ __launch_bounds__(256) void k_lse(const float* __restrict__ pm,
                                             const float* __restrict__ ps,
                                             float* __restrict__ lse) {
  int rho = blockIdx.x;
  int tid = threadIdx.x;
  float m = -1e30f, s = 0.f;
  for (int p = tid; p < NBLK_LOG; p += 256) {
    float pmv = pm[(size_t)rho * NBLK_LOG + p], psv = ps[(size_t)rho * NBLK_LOG + p];
    float nm = fmaxf(m, pmv);
    s = s * __expf(m - nm) + psv * __expf(pmv - nm);
    m = nm;
  }
  __shared__ float lm[256], ls[256];
  lm[tid] = m; ls[tid] = s;
  __syncthreads();
  for (int o = 128; o > 0; o >>= 1) {
    if (tid < o) {
      float m2 = lm[tid + o], s2 = ls[tid + o];
      float nm = fmaxf(lm[tid], m2);
      ls[tid] = ls[tid] * __expf(lm[tid] - nm) + s2 * __expf(m2 - nm);
      lm[tid] = nm;
    }
    __syncthreads();
  }
  if (tid == 0) lse[rho] = lm[0] + logf(ls[0]);
}

// vectorized subtract ; grid 1280 (rho = t'*64 + b, plane t'+1)
__global__ __launch_bounds__(256) void k_fin(float* __restrict__ out, const float* __restrict__ lse) {
  int rho = blockIdx.x;
  int tp = rho >> 6, b = rho & 63;
  float Lv = lse[rho];
  float* o = out + ((size_t)b * T_ + (tp + 1)) * V_;
  float4* o4 = (float4*)o;
  int tid = threadIdx.x;
  for (int i = tid; i < 12564; i += 256) {
    float4 v = o4[i];
    v.x -= Lv; v.y -= Lv; v.z -= Lv; v.w -= Lv;
    o4[i] = v;
  }
  if (tid == 0) o[50256] -= Lv;
}

/* ---------------- host ---------------- */

extern "C" void kernel_launch(void* const* d_in, const int* in_sizes, int n_in,
                              void* d_out, int out_size, void* d_ws, size_t ws_size,
                              hipStream_t stream) {
  const float* enc   = (const float*)d_in[0];
  const float* dih   = (const float*)d_in[1];
  const float* mask  = (const float*)d_in[2];
  const float* et    = (const float*)d_in[4];
  const float* Wih   = (const float*)d_in[5];
  const float* Whh   = (const float*)d_in[6];
  const float* bih   = (const float*)d_in[7];
  const float* bhh   = (const float*)d_in[8];
  const float* Waenc = (const float*)d_in[9];
  const float* Wah   = (const float*)d_in[10];
  const float* vatt  = (const float*)d_in[11];
  const float* Wout  = (const float*)d_in[12];
  const float* bout  = (const float*)d_in[13];
  const int*   ref   = (const int*)d_in[14];
  float* out = (float*)d_out;

  char* w = (char*)d_ws;
  size_t o = 0;
  unsigned short* Wb    = (unsigned short*)(w + o); o += (size_t)V_ * H_ * 2;
  unsigned short* Wfih  = (unsigned short*)(w + o); o += (size_t)1536 * 1024 * 2;
  unsigned short* Wfhh  = (unsigned short*)(w + o); o += (size_t)1536 * 512 * 2;
  unsigned short* WaTb  = (unsigned short*)(w + o); o += (size_t)512 * 512 * 2;
  unsigned short* WahTb = (unsigned short*)(w + o); o += (size_t)512 * 512 * 2;
  unsigned short* encb  = (unsigned short*)(w + o); o += (size_t)B_ * L_ * F_ * 2;
  unsigned short* epb   = (unsigned short*)(w + o); o += (size_t)B_ * L_ * A_ * 2;
  unsigned short* hsAll = (unsigned short*)(w + o); o += (size_t)T_ * BH * 2;
  float* hT0 = (float*)(w + o); o += (size_t)H_ * B_ * 4;
  float* hT1 = (float*)(w + o); o += (size_t)H_ * B_ * 4;
  unsigned short* xbf = (unsigned short*)(w + o); o += (size_t)B_ * D_ * 2;
  float* pm  = (float*)(w + o); o += (size_t)NROW * NBLK_LOG * 4;
  float* ps  = (float*)(w + o); o += (size_t)NROW * NBLK_LOG * 4;
  float* lse = (float*)(w + o); o += (size_t)NROW * 4;

  k_cvt<<<4096, 256, 0, stream>>>(Wout, Wb, V_ * H_ / 4);
  k_cvt<<<2048, 256, 0, stream>>>(enc, encb, B_ * L_ * F_ / 4);
  k_wfrag<<<96, 256, 0, stream>>>(Wih, Wfih, 1024);
  k_wfrag<<<96, 256, 0, stream>>>(Whh, Wfhh, 512);
  k_transcvt<<<dim3(8, 8), 256, 0, stream>>>(Waenc, WaTb, 512, 512);
  k_transcvt<<<dim3(8, 8), 256, 0, stream>>>(Wah, WahTb, 512, 512);
  k_trans32<<<dim3(8, 1), 256, 0, stream>>>(dih, hT0, 64, 512);
  k_hs0<<<64, 256, 0, stream>>>(dih, hsAll);
  k_encproj2<<<200, 256, 0, stream>>>(encb, WaTb, epb);
  k_zero0<<<dim3(50, 64), 256, 0, stream>>>(out);

  RecParams rp;
  rp.mask = mask; rp.et = et;
  rp.encb = encb; rp.epb = epb;
  rp.WahT = WahTb; rp.vatt = vatt;
  rp.Wfih = Wfih; rp.Wfhh = Wfhh;
  rp.bih = bih; rp.bhh = bhh;
  rp.Wb = Wb; rp.bout = bout;
  rp.ref = ref;
  rp.xbf = xbf;
  rp.pm = pm; rp.ps = ps; rp.lse = lse;
  rp.out = out;

  float* hTb[2] = {hT0, hT1};
  for (int t = 0; t < T_ - 1; ++t) {
    int cur = t & 1, nxt = cur ^ 1;
    unsigned short* hsold = hsAll + (size_t)t * BH;
    unsigned short* hsnew = hsAll + (size_t)(t + 1) * BH;
    k_att<<<64, 256, 0, stream>>>(rp, hsold, t);
    k_gru<<<32, 256, 0, stream>>>(rp, hsold, hTb[cur], hsnew, hTb[nxt]);
  }
  k_biggemm<<<NBLK_LOG, 256, 0, stream>>>(rp, hsAll);
  k_lse<<<1280, 256, 0, stream>>>(pm, ps, lse);
  k_fin<<<1280, 256, 0, stream>>>(out, lse);
}

// Round 6
// 2633.434 us; speedup vs baseline: 1.2737x; 1.2737x over previous
//
#include <hip/hip_runtime.h>
#include <stdint.h>
#include <stddef.h>

#define B_ 64
#define L_ 200
#define F_ 512
#define H_ 512
#define A_ 512
#define E_ 512
#define V_ 50257
#define T_ 21
#define D_ 1024
#define NBLK_LOG 786   /* ceil(V/64) */
#define BH (B_ * H_)
#define NROW 1280      /* 20 planes x 64 batch */

typedef __attribute__((ext_vector_type(8))) short short8;
typedef __attribute__((ext_vector_type(4))) float f32x4;

__device__ __forceinline__ unsigned short f2b(float f) {
  unsigned int u = __builtin_bit_cast(unsigned int, f);
  u += 0x7FFFu + ((u >> 16) & 1u);
  return (unsigned short)(u >> 16);
}
__device__ __forceinline__ float b2f(unsigned short s) {
  unsigned int u = ((unsigned int)s) << 16;
  return __builtin_bit_cast(float, u);
}
__device__ __forceinline__ f32x4 mfma16(short8 a, short8 b, f32x4 c) {
  return __builtin_amdgcn_mfma_f32_16x16x32_bf16(a, b, c, 0, 0, 0);
}
// fragment-ordered layout: element offset of M-row b, K-col j in a (64 x 512) plane
__device__ __forceinline__ int hsoff(int b, int j) {
  return (((b >> 4) * 16 + (j >> 5)) * 64 + (((j >> 3) & 3) * 16 + (b & 15))) * 8 + (j & 7);
}

/* ---------------- setup kernels ---------------- */

__global__ void k_cvt(const float* __restrict__ src, unsigned short* __restrict__ dst, int n4) {
  int i = blockIdx.x * blockDim.x + threadIdx.x;
  int stride = gridDim.x * blockDim.x;
  const float4* s4 = (const float4*)src;
  ushort4* d4 = (ushort4*)dst;
  for (; i < n4; i += stride) {
    float4 v = s4[i];
    ushort4 o;
    o.x = f2b(v.x); o.y = f2b(v.y); o.z = f2b(v.z); o.w = f2b(v.w);
    d4[i] = o;
  }
}

// row-sliced convert: dst[j][0:512] = bf16(src[j][srcoff : srcoff+512]) ; grid rows
__global__ void k_cvts(const float* __restrict__ src, unsigned short* __restrict__ dst,
                       int srcld, int srcoff) {
  int j = blockIdx.x;
  const float* s = src + (size_t)j * srcld + srcoff;
  unsigned short* d = dst + (size_t)j * 512;
  for (int k = threadIdx.x; k < 512; k += 256) d[k] = f2b(s[k]);
}

// src f32 (R,C) -> dst bf16 (C,R); grid (C/64, R/64), 256 thr
__global__ void k_transcvt(const float* __restrict__ src, unsigned short* __restrict__ dst, int R, int C) {
  __shared__ float tile[64][65];
  int cb = blockIdx.x * 64, rb = blockIdx.y * 64;
  int tx = threadIdx.x & 63, ty = threadIdx.x >> 6;
#pragma unroll
  for (int i = 0; i < 16; ++i) {
    int r = ty * 16 + i;
    tile[r][tx] = src[(size_t)(rb + r) * C + cb + tx];
  }
  __syncthreads();
#pragma unroll
  for (int i = 0; i < 16; ++i) {
    int c = ty * 16 + i;
    dst[(size_t)(cb + c) * R + rb + tx] = f2b(tile[tx][c]);
  }
}

// all-step embeddings -> fragment-ordered bf16 planes ; grid (64, 20), 64 thr
__global__ void k_embAll(const int* __restrict__ ref, const float* __restrict__ et,
                         unsigned short* __restrict__ embf) {
  int b = blockIdx.x, tp = blockIdx.y;
  int word = ref[b * T_ + tp];
  const float* er = et + (size_t)word * E_;
  unsigned short* dst = embf + (size_t)tp * BH;
  int c = threadIdx.x;  // 0..63
  const float4* s = (const float4*)(er + c * 8);
  float4 x = s[0], y = s[1];
  short8 o;
  o[0] = f2b(x.x); o[1] = f2b(x.y); o[2] = f2b(x.z); o[3] = f2b(x.w);
  o[4] = f2b(y.x); o[5] = f2b(y.y); o[6] = f2b(y.z); o[7] = f2b(y.w);
  *(short8*)(dst + hsoff(b, c * 8)) = o;
}

// epb[(b,l)][a] = sum_f encb[(b,l)][f] * WaTb[a][f] ; grid 200 blocks
__global__ __launch_bounds__(256, 2) void k_encproj2(const unsigned short* __restrict__ encb,
                                                     const unsigned short* __restrict__ WaTb,
                                                     unsigned short* __restrict__ epb) {
  __shared__ unsigned short al[32768];
  int tid = threadIdx.x;
  size_t rowbase = (size_t)blockIdx.x * 64;
  for (int idx = tid; idx < 4096; idx += 256) {
    int row = idx >> 6, seg = idx & 63;
    unsigned char* dp = (unsigned char*)al + row * 1024 + ((seg * 16) ^ ((row & 7) << 4));
    *(short8*)dp = *(const short8*)(encb + (rowbase + row) * F_ + seg * 8);
  }
  __syncthreads();
  int w = tid >> 6, lane = tid & 63, ln15 = lane & 15, g = lane >> 4;
  int sw = (ln15 & 7) << 4;
  const unsigned char* alb = (const unsigned char*)al;
  int mrow = w * 16 + ln15;
  for (int nt = 0; nt < 32; ++nt) {
    f32x4 acc = {0.f, 0.f, 0.f, 0.f};
    const unsigned short* brow = WaTb + (size_t)(nt * 16 + ln15) * F_ + 8 * g;
#pragma unroll 4
    for (int kk = 0; kk < 16; ++kk) {
      short8 bf = *(const short8*)(brow + kk * 32);
      short8 af = *(const short8*)(alb + mrow * 1024 + ((kk * 64 + 16 * g) ^ sw));
      acc = mfma16(af, bf, acc);
    }
#pragma unroll
    for (int r = 0; r < 4; ++r) {
      size_t m = rowbase + w * 16 + 4 * g + r;
      epb[m * A_ + nt * 16 + ln15] = f2b(acc[r]);
    }
  }
}

// giEmb[(tp*64+bi)][n] = sum_k embf[tp][bi][k] * Wih1b[n][k] ; grid (24, 20)
__global__ __launch_bounds__(256) void k_giemb(const unsigned short* __restrict__ embf,
                                               const unsigned short* __restrict__ Wih1b,
                                               float* __restrict__ giEmb) {
  int tid = threadIdx.x;
  int w = tid >> 6, lane = tid & 63, ln15 = lane & 15, g = lane >> 4;
  int ncol = blockIdx.x * 64 + w * 16 + ln15;
  int tp = blockIdx.y;
  const unsigned short* brow = Wih1b + (size_t)ncol * 512 + 8 * g;
  short8 wb[16];
#pragma unroll
  for (int kk = 0; kk < 16; ++kk) wb[kk] = *(const short8*)(brow + kk * 32);
  const unsigned short* hp = embf + (size_t)tp * BH;
#pragma unroll
  for (int mp = 0; mp < 2; ++mp) {
    f32x4 z4 = {0.f, 0.f, 0.f, 0.f};
    f32x4 acc0 = z4, acc1 = z4;
#pragma unroll
    for (int kk = 0; kk < 16; ++kk) {
      short8 a0 = *(const short8*)(hp + (((mp * 2 + 0) * 16 + kk) * 64 + lane) * 8);
      short8 a1 = *(const short8*)(hp + (((mp * 2 + 1) * 16 + kk) * 64 + lane) * 8);
      acc0 = mfma16(a0, wb[kk], acc0);
      acc1 = mfma16(a1, wb[kk], acc1);
    }
#pragma unroll
    for (int r = 0; r < 4; ++r) {
      int bi0 = (mp * 2 + 0) * 16 + 4 * g + r;
      int bi1 = (mp * 2 + 1) * 16 + 4 * g + r;
      giEmb[((size_t)tp * 64 + bi0) * 1536 + ncol] = acc0[r];
      giEmb[((size_t)tp * 64 + bi1) * 1536 + ncol] = acc1[r];
    }
  }
}

// out[:,0,:] = 0 ; grid (50, 64)
__global__ void k_zero0(float* __restrict__ out) {
  int b = blockIdx.y;
  float* o = out + (size_t)b * T_ * V_;
  int v0 = blockIdx.x * 1024 + threadIdx.x;
#pragma unroll
  for (int i = 0; i < 4; ++i) { int v = v0 + i * 256; if (v < V_) o[v] = 0.f; }
}

/* ---------------- params ---------------- */

struct RecParams {
  const float* mask;
  const unsigned short* encb; const unsigned short* epb;
  const unsigned short* WahT; const float* vatt;
  const unsigned short* Wih2b; const unsigned short* Whhb;
  const float* bih; const float* bhh;
};

/* ---------------- fused per-step kernel: 64 blocks x 1024 thr ---------------- */

__global__ __launch_bounds__(1024) void k_step(RecParams P, const float* __restrict__ hOld,
                                               float* __restrict__ hNew,
                                               unsigned short* __restrict__ hsNew,
                                               const float* __restrict__ giEmb, int t) {
  __shared__ struct {
    float hrowF[H_];
    float hw[A_];
    float sc[256];
    float ctxp[16][F_];
    float ctxF[F_];
    float gi[1536];
    float gh[1536];
    float hnew[H_];
  } S;
  int b = blockIdx.x;
  int tid = threadIdx.x;
  int w = tid >> 6, lane = tid & 63;

  for (int k = tid; k < H_; k += 1024) S.hrowF[k] = hOld[(size_t)b * H_ + k];
  __syncthreads();
  float hl[8];
#pragma unroll
  for (int j = 0; j < 8; ++j) hl[j] = S.hrowF[lane * 8 + j];

  // phase 1: hW[a] = WahT[a,:] . h
  for (int a = w; a < A_; a += 16) {
    short8 wv = *(const short8*)(P.WahT + (size_t)a * H_ + lane * 8);
    float p = 0.f;
#pragma unroll
    for (int j = 0; j < 8; ++j) p += b2f((unsigned short)wv[j]) * hl[j];
    for (int o = 1; o < 64; o <<= 1) p += __shfl_xor(p, o);
    if (lane == 0) S.hw[a] = p;
  }
  __syncthreads();
  float hwv[8], vv[8];
#pragma unroll
  for (int j = 0; j < 8; ++j) { hwv[j] = S.hw[lane * 8 + j]; vv[j] = P.vatt[lane * 8 + j]; }

  // phase 2: masked scores
  for (int l = w; l < L_; l += 16) {
    short8 ev = *(const short8*)(P.epb + ((size_t)b * L_ + l) * A_ + lane * 8);
    float p = 0.f;
#pragma unroll
    for (int j = 0; j < 8; ++j) {
      float x = b2f((unsigned short)ev[j]) + hwv[j];
      float e2 = __expf(x + x);
      float th = 1.f - 2.f / (e2 + 1.f);
      p += th * vv[j];
    }
    for (int o = 1; o < 64; o <<= 1) p += __shfl_xor(p, o);
    if (lane == 0) {
      float mk = P.mask[b * L_ + l];
      S.sc[l] = (mk > 0.f) ? p : -1e9f;
    }
  }
  __syncthreads();

  // phase 3: softmax over L (first wave)
  if (tid < 64) {
    float m = -1e30f;
    for (int l = tid; l < L_; l += 64) m = fmaxf(m, S.sc[l]);
    for (int o = 1; o < 64; o <<= 1) m = fmaxf(m, __shfl_xor(m, o));
    float s = 0.f;
    for (int l = tid; l < L_; l += 64) s += __expf(S.sc[l] - m);
    for (int o = 1; o < 64; o <<= 1) s += __shfl_xor(s, o);
    float inv = 1.f / s;
    for (int l = tid; l < L_; l += 64) S.sc[l] = __expf(S.sc[l] - m) * inv;
  }
  __syncthreads();

  // phase 4: ctx (f32)
  float cacc[8] = {0.f, 0.f, 0.f, 0.f, 0.f, 0.f, 0.f, 0.f};
  for (int l = w; l < L_; l += 16) {
    float aw = S.sc[l];
    short8 evv = *(const short8*)(P.encb + ((size_t)b * L_ + l) * F_ + lane * 8);
#pragma unroll
    for (int j = 0; j < 8; ++j) cacc[j] += aw * b2f((unsigned short)evv[j]);
  }
#pragma unroll
  for (int j = 0; j < 8; ++j) S.ctxp[w][lane * 8 + j] = cacc[j];
  __syncthreads();
  for (int f = tid; f < F_; f += 1024) {
    float c = 0.f;
#pragma unroll
    for (int q = 0; q < 16; ++q) c += S.ctxp[q][f];
    S.ctxF[f] = c;
  }
  __syncthreads();
  float xc[8];
#pragma unroll
  for (int j = 0; j < 8; ++j) xc[j] = S.ctxF[lane * 8 + j];

  // phase 5: gate row dots (wave-per-row). jr<1024 (r,z): only gi+gh sum needed.
  for (int i = 0; i < 96; ++i) {
    int jr = w * 96 + i;
    short8 w2 = *(const short8*)(P.Wih2b + (size_t)jr * 512 + lane * 8);
    short8 wh = *(const short8*)(P.Whhb + (size_t)jr * 512 + lane * 8);
    float s1 = 0.f, s2 = 0.f;
#pragma unroll
    for (int j = 0; j < 8; ++j) {
      s1 += b2f((unsigned short)w2[j]) * xc[j];
      s2 += b2f((unsigned short)wh[j]) * hl[j];
    }
    if (jr < 1024) {
      float s = s1 + s2;
      for (int o = 1; o < 64; o <<= 1) s += __shfl_xor(s, o);
      if (lane == 0) S.gi[jr] = s;
    } else {
      for (int o = 1; o < 64; o <<= 1) { s1 += __shfl_xor(s1, o); s2 += __shfl_xor(s2, o); }
      if (lane == 0) { S.gi[jr] = s1; S.gh[jr] = s2; }
    }
  }
  __syncthreads();

  // phase 6: gate math, 512 threads
  if (tid < 512) {
    int j = tid;
    const float* ge = giEmb + ((size_t)t * 64 + b) * 1536;
    float srz_r = ge[j] + S.gi[j] + P.bih[j] + P.bhh[j];
    float srz_z = ge[512 + j] + S.gi[512 + j] + P.bih[512 + j] + P.bhh[512 + j];
    float in_ = ge[1024 + j] + S.gi[1024 + j] + P.bih[1024 + j];
    float hn = S.gh[1024 + j] + P.bhh[1024 + j];
    float rg = 1.f / (1.f + __expf(-srz_r));
    float zg = 1.f / (1.f + __expf(-srz_z));
    float e2 = __expf(2.f * (in_ + rg * hn));
    float ng = 1.f - 2.f / (e2 + 1.f);
    float hv = (1.f - zg) * ng + zg * S.hrowF[j];
    S.hnew[j] = hv;
    hNew[(size_t)b * H_ + j] = hv;
  }
  __syncthreads();

  // write bf16 fragment-ordered plane
  if (tid < 64) {
    int c = tid;
    short8 o;
#pragma unroll
    for (int j = 0; j < 8; ++j) o[j] = f2b(S.hnew[c * 8 + j]);
    *(short8*)(hsNew + hsoff(b, c * 8)) = o;
  }
}

/* ---------------- logits: two-pass GEMM with LDS repack ---------------- */

__global__ __launch_bounds__(256) void k_blog(const unsigned short* __restrict__ Wb,
                                              const float* __restrict__ bout,
                                              const unsigned short* __restrict__ hsAll,
                                              float* __restrict__ pm, float* __restrict__ ps,
                                              const float* __restrict__ lse,
                                              float* __restrict__ out, int pass) {
  __shared__ float tile[64][68];
  __shared__ float redm[64][4], reds[64][4];
  int tid = threadIdx.x;
  int w = tid >> 6, lane = tid & 63, ln15 = lane & 15, g = lane >> 4;
  int vcol = blockIdx.x * 64 + w * 16 + ln15;
  bool vok = vcol < V_;
  int vr = vok ? vcol : (V_ - 1);
  const unsigned short* brow = Wb + (size_t)vr * H_ + 8 * g;
  short8 wb[16];
#pragma unroll
  for (int kk = 0; kk < 16; ++kk) wb[kk] = *(const short8*)(brow + kk * 32);
  float bo = bout[vr];
  int row = tid >> 2, seg = tid & 3;

  for (int t = 0; t < T_ - 1; ++t) {
    const unsigned short* hp = hsAll + (size_t)(t + 1) * BH;
#pragma unroll
    for (int mp = 0; mp < 2; ++mp) {
      f32x4 z4 = {0.f, 0.f, 0.f, 0.f};
      f32x4 acc0 = z4, acc1 = z4;
#pragma unroll
      for (int kk = 0; kk < 16; ++kk) {
        short8 a0 = *(const short8*)(hp + (((mp * 2 + 0) * 16 + kk) * 64 + lane) * 8);
        short8 a1 = *(const short8*)(hp + (((mp * 2 + 1) * 16 + kk) * 64 + lane) * 8);
        acc0 = mfma16(a0, wb[kk], acc0);
        acc1 = mfma16(a1, wb[kk], acc1);
      }
#pragma unroll
      for (int r = 0; r < 4; ++r) {
        int bi0 = (mp * 2 + 0) * 16 + 4 * g + r;
        int bi1 = (mp * 2 + 1) * 16 + 4 * g + r;
        tile[bi0][w * 16 + ln15] = vok ? acc0[r] + bo : -1e30f;
        tile[bi1][w * 16 + ln15] = vok ? acc1[r] + bo : -1e30f;
      }
    }
    __syncthreads();
    if (pass == 0) {
      float m = -1e30f;
#pragma unroll
      for (int i = 0; i < 16; ++i) m = fmaxf(m, tile[row][seg * 16 + i]);
      float s = 0.f;
#pragma unroll
      for (int i = 0; i < 16; ++i) s += __expf(tile[row][seg * 16 + i] - m);
      redm[row][seg] = m; reds[row][seg] = s;
      __syncthreads();
      if (seg == 0) {
        float m0 = redm[row][0], m1 = redm[row][1], m2 = redm[row][2], m3 = redm[row][3];
        float m4 = fmaxf(fmaxf(m0, m1), fmaxf(m2, m3));
        float s4 = reds[row][0] * __expf(m0 - m4) + reds[row][1] * __expf(m1 - m4) +
                   reds[row][2] * __expf(m2 - m4) + reds[row][3] * __expf(m3 - m4);
        size_t rho = (size_t)t * 64 + row;
        pm[rho * NBLK_LOG + blockIdx.x] = m4;
        ps[rho * NBLK_LOG + blockIdx.x] = s4;
      }
      __syncthreads();
    } else {
      float Lv = lse[(size_t)t * 64 + row];
      int cb = blockIdx.x * 64 + seg * 16;
      float* orow = out + ((size_t)row * T_ + (t + 1)) * V_ + cb;
      if (cb + 16 <= V_) {
#pragma unroll
        for (int q = 0; q < 4; ++q) {
          float4 v;
          v.x = tile[row][seg * 16 + q * 4 + 0] - Lv;
          v.y = tile[row][seg * 16 + q * 4 + 1] - Lv;
          v.z = tile[row][seg * 16 + q * 4 + 2] - Lv;
          v.w = tile[row][seg * 16 + q * 4 + 3] - Lv;
          *(float4*)(orow + q * 4) = v;
        }
      } else {
        for (int i = 0; i < 16; ++i)
          if (cb + i < V_) orow[i] = tile[row][seg * 16 + i] - Lv;
      }
      __syncthreads();
    }
  }
}

// merge partials -> lse[rho] ; grid 1280
__global__ __launch_bounds__(256) void k_lse(const float* __restrict__ pm,
                                             const float* __restrict__ ps,
                                             float* __restrict__ lse) {
  int rho = blockIdx.x;
  int tid = threadIdx.x;
  float m = -1e30f, s = 0.f;
  for (int p = tid; p < NBLK_LOG; p += 256) {
    float pmv = pm[(size_t)rho * NBLK_LOG + p], psv = ps[(size_t)rho * NBLK_LOG + p];
    float nm = fmaxf(m, pmv);
    s = s * __expf(m - nm) + psv * __expf(pmv - nm);
    m = nm;
  }
  __shared__ float lm[256], ls[256];
  lm[tid] = m; ls[tid] = s;
  __syncthreads();
  for (int o = 128; o > 0; o >>= 1) {
    if (tid < o) {
      float m2 = lm[tid + o], s2 = ls[tid + o];
      float nm = fmaxf(lm[tid], m2);
      ls[tid] = ls[tid] * __expf(lm[tid] - nm) + s2 * __expf(m2 - nm);
      lm[tid] = nm;
    }
    __syncthreads();
  }
  if (tid == 0) lse[rho] = lm[0] + logf(ls[0]);
}

/* ---------------- host ---------------- */

extern "C" void kernel_launch(void* const* d_in, const int* in_sizes, int n_in,
                              void* d_out, int out_size, void* d_ws, size_t ws_size,
                              hipStream_t stream) {
  const float* enc   = (const float*)d_in[0];
  const float* dih   = (const float*)d_in[1];
  const float* mask  = (const float*)d_in[2];
  const float* et    = (const float*)d_in[4];
  const float* Wih   = (const float*)d_in[5];
  const float* Whh   = (const float*)d_in[6];
  const float* bih   = (const float*)d_in[7];
  const float* bhh   = (const float*)d_in[8];
  const float* Waenc = (const float*)d_in[9];
  const float* Wah   = (const float*)d_in[10];
  const float* vatt  = (const float*)d_in[11];
  const float* Wout  = (const float*)d_in[12];
  const float* bout  = (const float*)d_in[13];
  const int*   ref   = (const int*)d_in[14];
  float* out = (float*)d_out;

  char* w = (char*)d_ws;
  size_t o = 0;
  unsigned short* Wb    = (unsigned short*)(w + o); o += (size_t)V_ * H_ * 2;
  unsigned short* Wih1b = (unsigned short*)(w + o); o += (size_t)1536 * 512 * 2;
  unsigned short* Wih2b = (unsigned short*)(w + o); o += (size_t)1536 * 512 * 2;
  unsigned short* Whhb  = (unsigned short*)(w + o); o += (size_t)1536 * 512 * 2;
  unsigned short* WaTb  = (unsigned short*)(w + o); o += (size_t)512 * 512 * 2;
  unsigned short* WahTb = (unsigned short*)(w + o); o += (size_t)512 * 512 * 2;
  unsigned short* encb  = (unsigned short*)(w + o); o += (size_t)B_ * L_ * F_ * 2;
  unsigned short* epb   = (unsigned short*)(w + o); o += (size_t)B_ * L_ * A_ * 2;
  unsigned short* embf  = (unsigned short*)(w + o); o += (size_t)20 * BH * 2;
  unsigned short* hsAll = (unsigned short*)(w + o); o += (size_t)T_ * BH * 2;
  float* hTAll = (float*)(w + o); o += (size_t)T_ * BH * 4;
  float* giEmb = (float*)(w + o); o += (size_t)NROW * 1536 * 4;
  float* pm  = (float*)(w + o); o += (size_t)NROW * NBLK_LOG * 4;
  float* ps  = (float*)(w + o); o += (size_t)NROW * NBLK_LOG * 4;
  float* lse = (float*)(w + o); o += (size_t)NROW * 4;

  k_cvt<<<4096, 256, 0, stream>>>(Wout, Wb, V_ * H_ / 4);
  k_cvt<<<2048, 256, 0, stream>>>(enc, encb, B_ * L_ * F_ / 4);
  k_cvts<<<1536, 256, 0, stream>>>(Wih, Wih1b, 1024, 0);
  k_cvts<<<1536, 256, 0, stream>>>(Wih, Wih2b, 1024, 512);
  k_cvts<<<1536, 256, 0, stream>>>(Whh, Whhb, 512, 0);
  k_transcvt<<<dim3(8, 8), 256, 0, stream>>>(Waenc, WaTb, 512, 512);
  k_transcvt<<<dim3(8, 8), 256, 0, stream>>>(Wah, WahTb, 512, 512);
  k_embAll<<<dim3(64, 20), 64, 0, stream>>>(ref, et, embf);
  k_encproj2<<<200, 256, 0, stream>>>(encb, WaTb, epb);
  k_giemb<<<dim3(24, 20), 256, 0, stream>>>(embf, Wih1b, giEmb);
  k_zero0<<<dim3(50, 64), 256, 0, stream>>>(out);

  RecParams rp;
  rp.mask = mask;
  rp.encb = encb; rp.epb = epb;
  rp.WahT = WahTb; rp.vatt = vatt;
  rp.Wih2b = Wih2b; rp.Whhb = Whhb;
  rp.bih = bih; rp.bhh = bhh;

  for (int t = 0; t < T_ - 1; ++t) {
    const float* hOld = (t == 0) ? dih : (hTAll + (size_t)t * BH);
    float* hNew = hTAll + (size_t)(t + 1) * BH;
    unsigned short* hsNew = hsAll + (size_t)(t + 1) * BH;
    k_step<<<64, 1024, 0, stream>>>(rp, hOld, hNew, hsNew, giEmb, t);
  }
  k_blog<<<NBLK_LOG, 256, 0, stream>>>(Wb, bout, hsAll, pm, ps, lse, out, 0);
  k_lse<<<1280, 256, 0, stream>>>(pm, ps, lse);
  k_blog<<<NBLK_LOG, 256, 0, stream>>>(Wb, bout, hsAll, pm, ps, lse, out, 1);
}